// Round 11
// baseline (283.287 us; speedup 1.0000x reference)
//
#include <hip/hip_runtime.h>
#include <cstdint>

using u16 = unsigned short;
typedef short bf16x8 __attribute__((ext_vector_type(8)));
typedef float f32x4 __attribute__((ext_vector_type(4)));

__device__ __forceinline__ float bf2f(u16 h) {
    union { unsigned u; float f; } x;
    x.u = ((unsigned)h) << 16;
    return x.f;
}
__device__ __forceinline__ u16 f2bf(float f) {
    union { float f; unsigned u; } x;
    x.f = f;
    unsigned r = x.u + 0x7fffu + ((x.u >> 16) & 1u);
    return (u16)(r >> 16);
}

// async global->LDS, 16B per lane; LDS dest is wave-uniform base + lane*16
__device__ __forceinline__ void gl_lds16(const u16* g, u16* l) {
    __builtin_amdgcn_global_load_lds((const __attribute__((address_space(1))) void*)g,
                                     (__attribute__((address_space(3))) void*)l, 16, 0, 0);
}

#define N1 8192
#define N2 2048
#define C2 256

// ---------------------------------------------------------------------------
// preproc: points2 transpose + w0/w1 cvt + stats/ctr zero.
// ---------------------------------------------------------------------------
__device__ __forceinline__ void tr_tile(const float* __restrict__ src,
                                        u16* __restrict__ dst,
                                        int C, int N, int ds, int b, int n0, int c0,
                                        int tid, float (*tile)[33]) {
    int tx = tid & 31, ty = tid >> 5;  // 32 x 8
    const float* s = src + (long)b * C * N;
#pragma unroll
    for (int i = 0; i < 4; i++) {
        int c = ty + i * 8;
        tile[c][tx] = s[(long)(c0 + c) * N + n0 + tx];
    }
    __syncthreads();
    u16* d = dst + (long)b * N * ds;
#pragma unroll
    for (int i = 0; i < 4; i++) {
        int n = ty + i * 8;
        d[(long)(n0 + n) * ds + c0 + tx] = f2bf(tile[tx][n]);
    }
}

__global__ __launch_bounds__(256) void preproc(const float* __restrict__ w0,
                                               const float* __restrict__ w1,
                                               const float* __restrict__ points2,
                                               u16* __restrict__ w0b,
                                               u16* __restrict__ w1b,
                                               u16* __restrict__ P2T,
                                               float* __restrict__ stats,
                                               unsigned* __restrict__ ctr) {
    __shared__ float tile[32][33];
    int bid = blockIdx.x, tid = threadIdx.x;
    if (bid < 4096) {
        int nb = bid & 63, cb = (bid >> 6) & 7, b = bid >> 9;
        tr_tile(points2, P2T, 256, 2048, 256, b, nb * 32, cb * 32, tid, tile);
    } else if (bid < 4480) {
        int i = (bid - 4096) * 256 + tid;
        w0b[i] = f2bf(w0[i]);
    } else if (bid < 4608) {
        int i = (bid - 4480) * 256 + tid;
        w1b[i] = f2bf(w1[i]);
    } else {
        for (int i = tid; i < 768; i += 256) stats[i] = 0.0f;
        if (tid == 0)
            __hip_atomic_store(ctr, 0u, __ATOMIC_RELAXED, __HIP_MEMORY_SCOPE_AGENT);
    }
}

// ---------------------------------------------------------------------------
// kNN(3) + interpolation — R17 FROZEN (242.9 µs config).
// ---------------------------------------------------------------------------
__global__ __launch_bounds__(512) void knn_interp(const float* __restrict__ xyz1,
                                                  const float* __restrict__ xyz2,
                                                  const float* __restrict__ points1,
                                                  const u16* __restrict__ P2T,  // [B][N2][C2]
                                                  u16* __restrict__ X) {       // [B*N1][384]
    __shared__ float4 pts[N2 / 2 + 16];  // 16640 B (scan stage; reused as p1 tile, stride-65)
    __shared__ float m_d[8][64][3];      // 6144 B partial top-3 (squared dist)
    __shared__ int   m_i[8][64][3];      // 6144 B
    __shared__ int   s_idx[64][3];
    __shared__ float s_w[64][3];
    int b = blockIdx.y;
    int n0 = blockIdx.x * 64;
    int tid = threadIdx.x;
    int ql = tid & 63;       // query within block
    int part = tid >> 6;     // candidate partition 0..7 (== wave id)

    int cp = tid >> 3;       // channel pair: channels 2cp, 2cp+1
    int g = tid & 7;         // n-octet within the 64-query tile
    const float* p1r0 = points1 + ((long)b * 128 + 2 * cp) * N1 + n0 + g * 8;
    const float* p1r1 = p1r0 + N1;
    float4 c0a = *(const float4*)(p1r0);
    float4 c0b = *(const float4*)(p1r0 + 4);
    float4 c1a = *(const float4*)(p1r1);
    float4 c1b = *(const float4*)(p1r1 + 4);
    asm volatile("" ::: "memory");

    int n = n0 + ql;
    float px = xyz1[((long)b * N1 + n) * 3 + 0];
    float py = xyz1[((long)b * N1 + n) * 3 + 1];
    float pz = xyz1[((long)b * N1 + n) * 3 + 2];
    float psq = __fadd_rn(__fadd_rn(__fmul_rn(px, px), __fmul_rn(py, py)), __fmul_rn(pz, pz));

    float b0 = 1e30f, b1 = 1e30f, b2 = 1e30f;
    int i0 = 0, i1 = 0, i2 = 0;

    for (int half = 0; half < 2; half++) {
        for (int j = tid; j < N2 / 2; j += 512) {
            int jg = half * (N2 / 2) + j;
            float x = xyz2[((long)b * N2 + jg) * 3 + 0];
            float y = xyz2[((long)b * N2 + jg) * 3 + 1];
            float z = xyz2[((long)b * N2 + jg) * 3 + 2];
            float nsq = __fadd_rn(__fadd_rn(__fmul_rn(x, x), __fmul_rn(y, y)), __fmul_rn(z, z));
            pts[j] = make_float4(x, y, z, nsq);
        }
        __syncthreads();

        int jbeg = half * (N2 / 2) + part * (N2 / 16);
        const float4* lp = &pts[part * (N2 / 16)];
#pragma unroll 8
        for (int jj = 0; jj < N2 / 16; jj++) {
            int j = jbeg + jj;
            float4 p = lp[jj];  // wave-uniform -> LDS broadcast
            float dot = __fadd_rn(__fadd_rn(__fmul_rn(px, p.x), __fmul_rn(py, p.y)),
                                  __fmul_rn(pz, p.z));
            float sq = __fsub_rn(__fadd_rn(psq, p.w), __fmul_rn(2.0f, dot));
            if (sq < b2) {
                if (sq < b1) {
                    b2 = b1; i2 = i1;
                    if (sq < b0) { b1 = b0; i1 = i0; b0 = sq; i0 = j; }
                    else         { b1 = sq; i1 = j; }
                } else { b2 = sq; i2 = j; }
            }
        }
        __syncthreads();  // scan done before half re-stage
    }

    m_d[part][ql][0] = b0; m_d[part][ql][1] = b1; m_d[part][ql][2] = b2;
    m_i[part][ql][0] = i0; m_i[part][ql][1] = i1; m_i[part][ql][2] = i2;
    __syncthreads();

    // ---- stage p1 tile into pts-alias (dead after scan), stride 65 u32 ----
    {
        unsigned* t32 = (unsigned*)pts;  // [64] rows x stride-65 u32, col = cp
        float r0[8] = {c0a.x, c0a.y, c0a.z, c0a.w, c0b.x, c0b.y, c0b.z, c0b.w};
        float r1[8] = {c1a.x, c1a.y, c1a.z, c1a.w, c1b.x, c1b.y, c1b.z, c1b.w};
#pragma unroll
        for (int k = 0; k < 8; k++) {
            unsigned v = (unsigned)f2bf(r0[k]) | ((unsigned)f2bf(r1[k]) << 16);
            t32[(g * 8 + k) * 65 + cp] = v;
        }
    }

    if (tid < 64) {
        float c0 = 1e30f, c1 = 1e30f, c2 = 1e30f;
        int a0 = 0x7fffffff, a1 = 0x7fffffff, a2 = 0x7fffffff;
#pragma unroll
        for (int pp = 0; pp < 8; pp++) {
#pragma unroll
            for (int k = 0; k < 3; k++) {
                float d = m_d[pp][tid][k];
                int ix = m_i[pp][tid][k];
                if (d < c2 || (d == c2 && ix < a2)) {
                    if (d < c1 || (d == c1 && ix < a1)) {
                        c2 = c1; a2 = a1;
                        if (d < c0 || (d == c0 && ix < a0)) { c1 = c0; a1 = a0; c0 = d; a0 = ix; }
                        else                                { c1 = d; a1 = ix; }
                    } else { c2 = d; a2 = ix; }
                }
            }
        }
        float e0 = sqrtf(fmaxf(c0, 0.0f));
        float e1 = sqrtf(fmaxf(c1, 0.0f));
        float e2 = sqrtf(fmaxf(c2, 0.0f));
        float kd0 = fmaxf(e0, 1e-10f), kd1 = fmaxf(e1, 1e-10f), kd2 = fmaxf(e2, 1e-10f);
        float w0 = __fdiv_rn(1.0f, kd0), w1 = __fdiv_rn(1.0f, kd1), w2 = __fdiv_rn(1.0f, kd2);
        float wsum = __fadd_rn(__fadd_rn(w0, w1), w2);
        s_idx[tid][0] = a0; s_idx[tid][1] = a1; s_idx[tid][2] = a2;
        s_w[tid][0] = __fdiv_rn(w0, wsum);
        s_w[tid][1] = __fdiv_rn(w1, wsum);
        s_w[tid][2] = __fdiv_rn(w2, wsum);
    }
    __syncthreads();

    // ---- coalesced X[:,0:128] store ----
    {
        const unsigned* t32 = (const unsigned*)pts;
        int p = tid >> 3, ch = tid & 7;
        unsigned v[8];
#pragma unroll
        for (int j = 0; j < 8; j++) v[j] = t32[p * 65 + ch * 8 + j];
        uint4* xo = (uint4*)(X + (long)(b * N1 + n0 + p) * 384);
        xo[ch * 2]     = make_uint4(v[0], v[1], v[2], v[3]);
        xo[ch * 2 + 1] = make_uint4(v[4], v[5], v[6], v[7]);
    }

    int l = tid & 63;
    const u16* base = P2T + (long)b * N2 * C2;
#pragma unroll 2
    for (int p = part; p < 64; p += 8) {
        int j0 = s_idx[p][0], j1 = s_idx[p][1], j2 = s_idx[p][2];  // broadcast
        float f0 = s_w[p][0], f1 = s_w[p][1], f2 = s_w[p][2];
        ushort4 r0 = *(const ushort4*)&base[(long)j0 * C2 + l * 4];
        ushort4 r1 = *(const ushort4*)&base[(long)j1 * C2 + l * 4];
        ushort4 r2 = *(const ushort4*)&base[(long)j2 * C2 + l * 4];
        ushort4 o;
        o.x = f2bf(__fadd_rn(__fadd_rn(__fmul_rn(bf2f(r0.x), f0), __fmul_rn(bf2f(r1.x), f1)),
                             __fmul_rn(bf2f(r2.x), f2)));
        o.y = f2bf(__fadd_rn(__fadd_rn(__fmul_rn(bf2f(r0.y), f0), __fmul_rn(bf2f(r1.y), f1)),
                             __fmul_rn(bf2f(r2.y), f2)));
        o.z = f2bf(__fadd_rn(__fadd_rn(__fmul_rn(bf2f(r0.z), f0), __fmul_rn(bf2f(r1.z), f1)),
                             __fmul_rn(bf2f(r2.z), f2)));
        o.w = f2bf(__fadd_rn(__fadd_rn(__fmul_rn(bf2f(r0.w), f0), __fmul_rn(bf2f(r1.w), f1)),
                             __fmul_rn(bf2f(r2.w), f2)));
        *(ushort4*)&X[(long)(b * N1 + n0 + p) * 384 + 128 + l * 4] = o;
    }
}

// ---------------------------------------------------------------------------
// bf16 MFMA GEMM. ASYNC (gemm0): R17-verbatim BK=64 two-sub staging (R19's
// vmcnt pipeline reverted — measured neutral-to-negative, per m131-m140).
// Non-ASYNC (gemm1): R17 BK=32 VGPR staging + fused input BN+ReLU.
// R20 FUSE (v2 of R18): finalize fused into gemm1 with ZERO LDS growth —
// tbuf aliases the Al/Bl region (dead after last MFMA; 20.5KB >= 16.5KB).
// R18's failure was LDS 40KB -> 3 blk/CU throttling the GEMM phase; now LDS
// stays ~23.6KB -> 6 blk/CU (1536 slots >= 512 blocks, co-residency safe).
// Spin grid-barrier + in-register BN1+ReLU + LDS transpose + coalesced
// float4 out stores. Y1 never touches HBM; finalize_k deleted.
// ---------------------------------------------------------------------------
template <int KDIM, bool BN_IN, bool ASYNC, bool SWZ, bool FUSE>
__global__ __launch_bounds__(256) void gemm_bn(const u16* __restrict__ A,
                                               const u16* __restrict__ Bw,
                                               const float* __restrict__ bias,
                                               const float* __restrict__ g_in_sum,
                                               const float* __restrict__ g_in_ssq,
                                               const float* __restrict__ gamma_in,
                                               const float* __restrict__ beta_in,
                                               u16* __restrict__ Yout, int Ntot,
                                               float* __restrict__ g_out_sum,
                                               float* __restrict__ g_out_ssq,
                                               const float* __restrict__ gamma_out,
                                               const float* __restrict__ beta_out,
                                               float* __restrict__ out,
                                               unsigned* __restrict__ ctr) {
    constexpr int LDSZ = ASYNC ? 2 * 128 * 32 : 128 * 40;  // u16 elems per array
    constexpr int SUB = 128 * 32;                          // sub-tile size (ASYNC)
    __shared__ __align__(16) u16 smem[2 * LDSZ];   // Al | Bl (tbuf aliases in FUSE)
    __shared__ float s_stats[256];
    __shared__ float s_scale[BN_IN ? KDIM : 2];
    __shared__ float s_shift[BN_IN ? KDIM : 2];
    u16* Al = smem;
    u16* Bl = smem + LDSZ;

    int tid = threadIdx.x;
    long s0;
    int o0;
    if constexpr (SWZ) {
        int bid = blockIdx.x;
        int xcd = bid & 7;
        int i = bid >> 3;               // 0..127 within XCD
        int u = xcd * 64 + (i >> 1);    // pair (row-tile) id 0..511
        s0 = (long)u * 128;
        o0 = (i & 1) * 128;
    } else {
        s0 = (long)blockIdx.y * 128;    // row tile
        o0 = blockIdx.x * 128;          // col tile
    }

    s_stats[tid] = 0.0f;
    if constexpr (BN_IN) {
        for (int k = tid; k < KDIM; k += 256) {
            float mu = g_in_sum[k] * (1.0f / 65536.0f);
            float var = g_in_ssq[k] * (1.0f / 65536.0f) - mu * mu;
            float rs = rsqrtf(var + 1e-5f);
            float sc = gamma_in[k] * rs;
            s_scale[k] = sc;
            s_shift[k] = beta_in[k] - mu * sc;
        }
    }
    int wid = tid >> 6, lane = tid & 63;
    int wm = wid >> 1, wn = wid & 1;
    int q = lane >> 4, l16 = lane & 15;

    f32x4 acc[4][4];
#pragma unroll
    for (int mi = 0; mi < 4; mi++)
#pragma unroll
        for (int ni = 0; ni < 4; ni++) acc[mi][ni] = (f32x4){0.f, 0.f, 0.f, 0.f};

    int rbase0 = wid * 32;
    int rsub = lane >> 2;
    int colsw = (((lane & 3) ^ (rsub & 3)) << 3);
    const u16* gA0 = A + (s0 + rbase0 + rsub) * KDIM + colsw;
    const u16* gA1 = gA0 + (long)16 * KDIM;
    const u16* gB0 = Bw + (long)(o0 + rbase0 + rsub) * KDIM + colsw;
    const u16* gB1 = gB0 + (long)16 * KDIM;
    u16* lA0 = &Al[rbase0 * 32];
    u16* lA1 = &Al[(rbase0 + 16) * 32];
    u16* lB0 = &Bl[rbase0 * 32];
    u16* lB1 = &Bl[(rbase0 + 16) * 32];
    int qA = ASYNC ? (q ^ (l16 & 3)) : q;

    __syncthreads();

    if constexpr (ASYNC) {
        for (int kt = 0; kt < KDIM; kt += 64) {
#pragma unroll
            for (int sub = 0; sub < 2; sub++) {
                int ko = kt + sub * 32;
                gl_lds16(gA0 + ko, lA0 + sub * SUB);
                gl_lds16(gA1 + ko, lA1 + sub * SUB);
                gl_lds16(gB0 + ko, lB0 + sub * SUB);
                gl_lds16(gB1 + ko, lB1 + sub * SUB);
            }
            __syncthreads();
#pragma unroll
            for (int sub = 0; sub < 2; sub++) {
                bf16x8 af[4], bfr[4];
#pragma unroll
                for (int mi = 0; mi < 4; mi++)
                    af[mi] = *(const bf16x8*)&Al[sub * SUB + (wm * 64 + mi * 16 + l16) * 32 + qA * 8];
#pragma unroll
                for (int ni = 0; ni < 4; ni++)
                    bfr[ni] = *(const bf16x8*)&Bl[sub * SUB + (wn * 64 + ni * 16 + l16) * 32 + qA * 8];
#pragma unroll
                for (int mi = 0; mi < 4; mi++)
#pragma unroll
                    for (int ni = 0; ni < 4; ni++)
                        acc[mi][ni] = __builtin_amdgcn_mfma_f32_16x16x32_bf16(af[mi], bfr[ni],
                                                                              acc[mi][ni], 0, 0, 0);
            }
            __syncthreads();
        }
    } else {
        for (int kt = 0; kt < KDIM; kt += 32) {
#pragma unroll
            for (int cc = 0; cc < 2; cc++) {
                int ci = tid + cc * 256;
                int row = ci >> 2;
                int kc = (ci & 3) << 3;
                union { uint4 u; u16 h[8]; } va;
                va.u = *(const uint4*)(A + (s0 + row) * KDIM + kt + kc);
                if constexpr (BN_IN) {
#pragma unroll
                    for (int j = 0; j < 8; j++) {
                        float f = bf2f(va.h[j]);
                        f = fmaxf(fmaf(f, s_scale[kt + kc + j], s_shift[kt + kc + j]), 0.0f);
                        va.h[j] = f2bf(f);
                    }
                }
                *(uint4*)&Al[row * 40 + kc] = va.u;
                *(uint4*)&Bl[row * 40 + kc] = *(const uint4*)(Bw + (long)(o0 + row) * KDIM + kt + kc);
            }
            __syncthreads();
            bf16x8 af[4], bfr[4];
#pragma unroll
            for (int mi = 0; mi < 4; mi++)
                af[mi] = *(const bf16x8*)&Al[(wm * 64 + mi * 16 + l16) * 40 + qA * 8];
#pragma unroll
            for (int ni = 0; ni < 4; ni++)
                bfr[ni] = *(const bf16x8*)&Bl[(wn * 64 + ni * 16 + l16) * 40 + qA * 8];
#pragma unroll
            for (int mi = 0; mi < 4; mi++)
#pragma unroll
                for (int ni = 0; ni < 4; ni++)
                    acc[mi][ni] = __builtin_amdgcn_mfma_f32_16x16x32_bf16(af[mi], bfr[ni],
                                                                          acc[mi][ni], 0, 0, 0);
            __syncthreads();
        }
    }

    float bzs[4];
#pragma unroll
    for (int ni = 0; ni < 4; ni++) {
        int coll = wn * 64 + ni * 16 + l16;
        int col = o0 + coll;
        float bz = bias[col];
        bzs[ni] = bz;
        float s1 = 0.0f, s2 = 0.0f;
#pragma unroll
        for (int mi = 0; mi < 4; mi++) {
#pragma unroll
            for (int r = 0; r < 4; r++) {
                float v = acc[mi][ni][r] + bz;
                s1 += v;
                s2 += v * v;
                if constexpr (!FUSE) {
                    long row = s0 + wm * 64 + mi * 16 + q * 4 + r;
                    Yout[row * Ntot + col] = f2bf(v);
                }
            }
        }
        s1 += __shfl_xor(s1, 16, 64);
        s1 += __shfl_xor(s1, 32, 64);
        s2 += __shfl_xor(s2, 16, 64);
        s2 += __shfl_xor(s2, 32, 64);
        if (q == 0) {
            atomicAdd(&s_stats[coll], s1);
            atomicAdd(&s_stats[128 + coll], s2);
        }
    }
    __syncthreads();
    if (tid < 128) {
        atomicAdd(&g_out_sum[o0 + tid], s_stats[tid]);
        atomicAdd(&g_out_ssq[o0 + tid], s_stats[128 + tid]);
    }

    if constexpr (FUSE) {
        float (*tbuf)[129] = (float(*)[129])smem;  // aliases Al/Bl (dead now)
        __syncthreads();                  // drain stats atomics + last smem reads
        if (tid == 0) {
            __threadfence();
            atomicAdd(ctr, 1u);
            while (__hip_atomic_load(ctr, __ATOMIC_ACQUIRE, __HIP_MEMORY_SCOPE_AGENT)
                   < gridDim.y)
                __builtin_amdgcn_s_sleep(2);
        }
        __syncthreads();
        // BN1 scale/shift from completed global stats (agent-scope loads)
        if (tid < 128) {
            float su = __hip_atomic_load(&g_out_sum[tid], __ATOMIC_RELAXED,
                                         __HIP_MEMORY_SCOPE_AGENT);
            float sq = __hip_atomic_load(&g_out_ssq[tid], __ATOMIC_RELAXED,
                                         __HIP_MEMORY_SCOPE_AGENT);
            float mu = su * (1.0f / 65536.0f);
            float var = sq * (1.0f / 65536.0f) - mu * mu;
            float rs = rsqrtf(var + 1e-5f);
            float sc = gamma_out[tid] * rs;
            s_stats[tid] = sc;
            s_stats[128 + tid] = beta_out[tid] - mu * sc;
        }
        __syncthreads();
        int b = (int)(s0 >> 13);
        int nb = (int)(s0 & 8191);
        // 4 chunks of 32 cols: in-register BN1+ReLU -> LDS transpose ->
        // coalesced float4 stores (col = t>>3, 8 segs of 16 n each).
        for (int c = 0; c < 4; c++) {
            if (wn == (c >> 1)) {
#pragma unroll
                for (int nis = 0; nis < 2; nis++) {
                    int ni = (c & 1) * 2 + nis;
                    int coll = wn * 64 + ni * 16 + l16;
                    float sc = s_stats[coll], sh = s_stats[128 + coll];
                    float bz = bzs[ni];
#pragma unroll
                    for (int mi = 0; mi < 4; mi++)
#pragma unroll
                        for (int r = 0; r < 4; r++) {
                            float v = fmaxf(fmaf(acc[mi][ni][r] + bz, sc, sh), 0.0f);
                            tbuf[nis * 16 + l16][wm * 64 + mi * 16 + q * 4 + r] = v;
                        }
                }
            }
            __syncthreads();
            {
                int cl = tid >> 3, seg = tid & 7;
                const float* tr = &tbuf[cl][seg * 16];
                float* orow = out + ((long)b * 128 + c * 32 + cl) * 8192 + nb + seg * 16;
#pragma unroll
                for (int j = 0; j < 4; j++)
                    *(float4*)(orow + j * 4) =
                        make_float4(tr[j * 4], tr[j * 4 + 1], tr[j * 4 + 2], tr[j * 4 + 3]);
            }
            __syncthreads();
        }
    }
}

// ---------------------------------------------------------------------------
// launch (4 dispatches — finalize fused into gemm1)
// ---------------------------------------------------------------------------
extern "C" void kernel_launch(void* const* d_in, const int* in_sizes, int n_in,
                              void* d_out, int out_size, void* d_ws, size_t ws_size,
                              hipStream_t stream) {
    const float* xyz1    = (const float*)d_in[0];
    const float* xyz2    = (const float*)d_in[1];
    const float* points1 = (const float*)d_in[2];
    const float* points2 = (const float*)d_in[3];
    const float* w0 = (const float*)d_in[4];
    const float* b0 = (const float*)d_in[5];
    const float* gamma0 = (const float*)d_in[6];
    const float* beta0 = (const float*)d_in[7];
    const float* w1 = (const float*)d_in[8];
    const float* b1 = (const float*)d_in[9];
    const float* gamma1 = (const float*)d_in[10];
    const float* beta1 = (const float*)d_in[11];
    float* out = (float*)d_out;

    char* ws = (char*)d_ws;
    u16* X       = (u16*)(ws + 0);             // 65536 x 384 bf16 = 50,331,648
    u16* P2T     = (u16*)(ws + 50331648);      // 8,388,608
    u16* w0b     = (u16*)(ws + 58720256);      // 196,608
    u16* w1b     = (u16*)(ws + 58916864);      // 65,536
    u16* Y0      = (u16*)(ws + 58982400);      // 33,554,432
    unsigned* ctr = (unsigned*)(ws + 92536832); // reuses old Y1b region
    float* stats = (float*)(ws + 109314048);   // 3,072
    if (ws_size < 109317120) return;
    float* gsum0 = stats;
    float* gss0  = stats + 256;
    float* gsum1 = stats + 512;
    float* gss1  = stats + 640;

    preproc<<<4609, 256, 0, stream>>>(w0, w1, points2, w0b, w1b, P2T, stats, ctr);
    knn_interp<<<dim3(128, 8), 512, 0, stream>>>(xyz1, xyz2, points1, P2T, X);
    gemm_bn<384, false, true, true, false><<<1024, 256, 0, stream>>>(
        X, w0b, b0, nullptr, nullptr, nullptr, nullptr, Y0, 256, gsum0, gss0,
        nullptr, nullptr, nullptr, nullptr);
    gemm_bn<256, true, false, false, true><<<dim3(1, 512), 256, 0, stream>>>(
        Y0, w1b, b1, gsum0, gss0, gamma0, beta0, nullptr, 128, gsum1, gss1,
        gamma1, beta1, out, ctr);
}

// Round 12
// 248.245 us; speedup vs baseline: 1.1412x; 1.1412x over previous
//
#include <hip/hip_runtime.h>
#include <cstdint>

using u16 = unsigned short;
typedef short bf16x8 __attribute__((ext_vector_type(8)));
typedef float f32x4 __attribute__((ext_vector_type(4)));

__device__ __forceinline__ float bf2f(u16 h) {
    union { unsigned u; float f; } x;
    x.u = ((unsigned)h) << 16;
    return x.f;
}
__device__ __forceinline__ u16 f2bf(float f) {
    union { float f; unsigned u; } x;
    x.f = f;
    unsigned r = x.u + 0x7fffu + ((x.u >> 16) & 1u);
    return (u16)(r >> 16);
}

// async global->LDS, 16B per lane; LDS dest is wave-uniform base + lane*16
__device__ __forceinline__ void gl_lds16(const u16* g, u16* l) {
    __builtin_amdgcn_global_load_lds((const __attribute__((address_space(1))) void*)g,
                                     (__attribute__((address_space(3))) void*)l, 16, 0, 0);
}

#define N1 8192
#define N2 2048
#define C2 256

// ---------------------------------------------------------------------------
// preproc (R17): points2 transpose + w0/w1 cvt + stats zero.
// ---------------------------------------------------------------------------
__device__ __forceinline__ void tr_tile(const float* __restrict__ src,
                                        u16* __restrict__ dst,
                                        int C, int N, int ds, int b, int n0, int c0,
                                        int tid, float (*tile)[33]) {
    int tx = tid & 31, ty = tid >> 5;  // 32 x 8
    const float* s = src + (long)b * C * N;
#pragma unroll
    for (int i = 0; i < 4; i++) {
        int c = ty + i * 8;
        tile[c][tx] = s[(long)(c0 + c) * N + n0 + tx];
    }
    __syncthreads();
    u16* d = dst + (long)b * N * ds;
#pragma unroll
    for (int i = 0; i < 4; i++) {
        int n = ty + i * 8;
        d[(long)(n0 + n) * ds + c0 + tx] = f2bf(tile[tx][n]);
    }
}

__global__ __launch_bounds__(256) void preproc(const float* __restrict__ w0,
                                               const float* __restrict__ w1,
                                               const float* __restrict__ points2,
                                               u16* __restrict__ w0b,
                                               u16* __restrict__ w1b,
                                               u16* __restrict__ P2T,
                                               float* __restrict__ stats) {
    __shared__ float tile[32][33];
    int bid = blockIdx.x, tid = threadIdx.x;
    if (bid < 4096) {
        int nb = bid & 63, cb = (bid >> 6) & 7, b = bid >> 9;
        tr_tile(points2, P2T, 256, 2048, 256, b, nb * 32, cb * 32, tid, tile);
    } else if (bid < 4480) {
        int i = (bid - 4096) * 256 + tid;
        w0b[i] = f2bf(w0[i]);
    } else if (bid < 4608) {
        int i = (bid - 4480) * 256 + tid;
        w1b[i] = f2bf(w1[i]);
    } else {
        for (int i = tid; i < 768; i += 256) stats[i] = 0.0f;
    }
}

// ---------------------------------------------------------------------------
// kNN(3) + interpolation — R17 FROZEN (242.9 µs config).
// ---------------------------------------------------------------------------
__global__ __launch_bounds__(512) void knn_interp(const float* __restrict__ xyz1,
                                                  const float* __restrict__ xyz2,
                                                  const float* __restrict__ points1,
                                                  const u16* __restrict__ P2T,  // [B][N2][C2]
                                                  u16* __restrict__ X) {       // [B*N1][384]
    __shared__ float4 pts[N2 / 2 + 16];  // 16640 B (scan stage; reused as p1 tile, stride-65)
    __shared__ float m_d[8][64][3];      // 6144 B partial top-3 (squared dist)
    __shared__ int   m_i[8][64][3];      // 6144 B
    __shared__ int   s_idx[64][3];
    __shared__ float s_w[64][3];
    int b = blockIdx.y;
    int n0 = blockIdx.x * 64;
    int tid = threadIdx.x;
    int ql = tid & 63;       // query within block
    int part = tid >> 6;     // candidate partition 0..7 (== wave id)

    int cp = tid >> 3;       // channel pair: channels 2cp, 2cp+1
    int g = tid & 7;         // n-octet within the 64-query tile
    const float* p1r0 = points1 + ((long)b * 128 + 2 * cp) * N1 + n0 + g * 8;
    const float* p1r1 = p1r0 + N1;
    float4 c0a = *(const float4*)(p1r0);
    float4 c0b = *(const float4*)(p1r0 + 4);
    float4 c1a = *(const float4*)(p1r1);
    float4 c1b = *(const float4*)(p1r1 + 4);
    asm volatile("" ::: "memory");

    int n = n0 + ql;
    float px = xyz1[((long)b * N1 + n) * 3 + 0];
    float py = xyz1[((long)b * N1 + n) * 3 + 1];
    float pz = xyz1[((long)b * N1 + n) * 3 + 2];
    float psq = __fadd_rn(__fadd_rn(__fmul_rn(px, px), __fmul_rn(py, py)), __fmul_rn(pz, pz));

    float b0 = 1e30f, b1 = 1e30f, b2 = 1e30f;
    int i0 = 0, i1 = 0, i2 = 0;

    for (int half = 0; half < 2; half++) {
        for (int j = tid; j < N2 / 2; j += 512) {
            int jg = half * (N2 / 2) + j;
            float x = xyz2[((long)b * N2 + jg) * 3 + 0];
            float y = xyz2[((long)b * N2 + jg) * 3 + 1];
            float z = xyz2[((long)b * N2 + jg) * 3 + 2];
            float nsq = __fadd_rn(__fadd_rn(__fmul_rn(x, x), __fmul_rn(y, y)), __fmul_rn(z, z));
            pts[j] = make_float4(x, y, z, nsq);
        }
        __syncthreads();

        int jbeg = half * (N2 / 2) + part * (N2 / 16);
        const float4* lp = &pts[part * (N2 / 16)];
#pragma unroll 8
        for (int jj = 0; jj < N2 / 16; jj++) {
            int j = jbeg + jj;
            float4 p = lp[jj];  // wave-uniform -> LDS broadcast
            float dot = __fadd_rn(__fadd_rn(__fmul_rn(px, p.x), __fmul_rn(py, p.y)),
                                  __fmul_rn(pz, p.z));
            float sq = __fsub_rn(__fadd_rn(psq, p.w), __fmul_rn(2.0f, dot));
            if (sq < b2) {
                if (sq < b1) {
                    b2 = b1; i2 = i1;
                    if (sq < b0) { b1 = b0; i1 = i0; b0 = sq; i0 = j; }
                    else         { b1 = sq; i1 = j; }
                } else { b2 = sq; i2 = j; }
            }
        }
        __syncthreads();  // scan done before half re-stage
    }

    m_d[part][ql][0] = b0; m_d[part][ql][1] = b1; m_d[part][ql][2] = b2;
    m_i[part][ql][0] = i0; m_i[part][ql][1] = i1; m_i[part][ql][2] = i2;
    __syncthreads();

    // ---- stage p1 tile into pts-alias (dead after scan), stride 65 u32 ----
    {
        unsigned* t32 = (unsigned*)pts;  // [64] rows x stride-65 u32, col = cp
        float r0[8] = {c0a.x, c0a.y, c0a.z, c0a.w, c0b.x, c0b.y, c0b.z, c0b.w};
        float r1[8] = {c1a.x, c1a.y, c1a.z, c1a.w, c1b.x, c1b.y, c1b.z, c1b.w};
#pragma unroll
        for (int k = 0; k < 8; k++) {
            unsigned v = (unsigned)f2bf(r0[k]) | ((unsigned)f2bf(r1[k]) << 16);
            t32[(g * 8 + k) * 65 + cp] = v;
        }
    }

    if (tid < 64) {
        float c0 = 1e30f, c1 = 1e30f, c2 = 1e30f;
        int a0 = 0x7fffffff, a1 = 0x7fffffff, a2 = 0x7fffffff;
#pragma unroll
        for (int pp = 0; pp < 8; pp++) {
#pragma unroll
            for (int k = 0; k < 3; k++) {
                float d = m_d[pp][tid][k];
                int ix = m_i[pp][tid][k];
                if (d < c2 || (d == c2 && ix < a2)) {
                    if (d < c1 || (d == c1 && ix < a1)) {
                        c2 = c1; a2 = a1;
                        if (d < c0 || (d == c0 && ix < a0)) { c1 = c0; a1 = a0; c0 = d; a0 = ix; }
                        else                                { c1 = d; a1 = ix; }
                    } else { c2 = d; a2 = ix; }
                }
            }
        }
        float e0 = sqrtf(fmaxf(c0, 0.0f));
        float e1 = sqrtf(fmaxf(c1, 0.0f));
        float e2 = sqrtf(fmaxf(c2, 0.0f));
        float kd0 = fmaxf(e0, 1e-10f), kd1 = fmaxf(e1, 1e-10f), kd2 = fmaxf(e2, 1e-10f);
        float w0 = __fdiv_rn(1.0f, kd0), w1 = __fdiv_rn(1.0f, kd1), w2 = __fdiv_rn(1.0f, kd2);
        float wsum = __fadd_rn(__fadd_rn(w0, w1), w2);
        s_idx[tid][0] = a0; s_idx[tid][1] = a1; s_idx[tid][2] = a2;
        s_w[tid][0] = __fdiv_rn(w0, wsum);
        s_w[tid][1] = __fdiv_rn(w1, wsum);
        s_w[tid][2] = __fdiv_rn(w2, wsum);
    }
    __syncthreads();

    // ---- coalesced X[:,0:128] store ----
    {
        const unsigned* t32 = (const unsigned*)pts;
        int p = tid >> 3, ch = tid & 7;
        unsigned v[8];
#pragma unroll
        for (int j = 0; j < 8; j++) v[j] = t32[p * 65 + ch * 8 + j];
        uint4* xo = (uint4*)(X + (long)(b * N1 + n0 + p) * 384);
        xo[ch * 2]     = make_uint4(v[0], v[1], v[2], v[3]);
        xo[ch * 2 + 1] = make_uint4(v[4], v[5], v[6], v[7]);
    }

    int l = tid & 63;
    const u16* base = P2T + (long)b * N2 * C2;
#pragma unroll 2
    for (int p = part; p < 64; p += 8) {
        int j0 = s_idx[p][0], j1 = s_idx[p][1], j2 = s_idx[p][2];  // broadcast
        float f0 = s_w[p][0], f1 = s_w[p][1], f2 = s_w[p][2];
        ushort4 r0 = *(const ushort4*)&base[(long)j0 * C2 + l * 4];
        ushort4 r1 = *(const ushort4*)&base[(long)j1 * C2 + l * 4];
        ushort4 r2 = *(const ushort4*)&base[(long)j2 * C2 + l * 4];
        ushort4 o;
        o.x = f2bf(__fadd_rn(__fadd_rn(__fmul_rn(bf2f(r0.x), f0), __fmul_rn(bf2f(r1.x), f1)),
                             __fmul_rn(bf2f(r2.x), f2)));
        o.y = f2bf(__fadd_rn(__fadd_rn(__fmul_rn(bf2f(r0.y), f0), __fmul_rn(bf2f(r1.y), f1)),
                             __fmul_rn(bf2f(r2.y), f2)));
        o.z = f2bf(__fadd_rn(__fadd_rn(__fmul_rn(bf2f(r0.z), f0), __fmul_rn(bf2f(r1.z), f1)),
                             __fmul_rn(bf2f(r2.z), f2)));
        o.w = f2bf(__fadd_rn(__fadd_rn(__fmul_rn(bf2f(r0.w), f0), __fmul_rn(bf2f(r1.w), f1)),
                             __fmul_rn(bf2f(r2.w), f2)));
        *(ushort4*)&X[(long)(b * N1 + n0 + p) * 384 + 128 + l * 4] = o;
    }
}

// ---------------------------------------------------------------------------
// bf16 MFMA GEMM. R21 ASYNC (gemm0): BK=64 COALESCED staging — each gl_lds16
// covers 8 rows x 128B (full L2 lines; old layout read 16 rows x 64B
// half-lines -> 2x VMEM transactions). Global source column pre-swizzled
// slot -> slot^(row&7); LDS dest LINEAR (gl_lds16 writes base+lane*16);
// read side applies the same XOR -> all 8 slots covered per 16-lane group
// = 2-way banks (free; old layout was 4-way). Same LDS bytes ([128][64]
// u16 = 16KB/array), same 8 calls/wave/kt, same 2-barrier loop (R19's
// vmcnt pipeline measured neutral), ascending-k accumulation -> bitwise-
// identical output. Non-ASYNC (gemm1): R17 verbatim.
// R18/R20 grid-barrier fusion abandoned (spin cost ~50µs, twice measured).
// ---------------------------------------------------------------------------
template <int KDIM, bool BN_IN, bool ASYNC, bool SWZ>
__global__ __launch_bounds__(256) void gemm_bn(const u16* __restrict__ A,
                                               const u16* __restrict__ Bw,
                                               const float* __restrict__ bias,
                                               const float* __restrict__ g_in_sum,
                                               const float* __restrict__ g_in_ssq,
                                               const float* __restrict__ gamma_in,
                                               const float* __restrict__ beta_in,
                                               u16* __restrict__ Yout, int Ntot,
                                               float* __restrict__ g_out_sum,
                                               float* __restrict__ g_out_ssq) {
    constexpr int LDSZ = ASYNC ? 2 * 128 * 32 : 128 * 40;  // u16 elems
    __shared__ __align__(16) u16 Al[LDSZ];
    __shared__ __align__(16) u16 Bl[LDSZ];
    __shared__ float s_stats[256];
    __shared__ float s_scale[BN_IN ? KDIM : 2];
    __shared__ float s_shift[BN_IN ? KDIM : 2];

    int tid = threadIdx.x;
    long s0;
    int o0;
    if constexpr (SWZ) {
        int bid = blockIdx.x;
        int xcd = bid & 7;
        int i = bid >> 3;               // 0..127 within XCD
        int u = xcd * 64 + (i >> 1);    // pair (row-tile) id 0..511
        s0 = (long)u * 128;
        o0 = (i & 1) * 128;
    } else {
        s0 = (long)blockIdx.y * 128;    // row tile
        o0 = blockIdx.x * 128;          // col tile
    }

    s_stats[tid] = 0.0f;
    if constexpr (BN_IN) {
        for (int k = tid; k < KDIM; k += 256) {
            float mu = g_in_sum[k] * (1.0f / 65536.0f);
            float var = g_in_ssq[k] * (1.0f / 65536.0f) - mu * mu;
            float rs = rsqrtf(var + 1e-5f);
            float sc = gamma_in[k] * rs;
            s_scale[k] = sc;
            s_shift[k] = beta_in[k] - mu * sc;
        }
    }
    int wid = tid >> 6, lane = tid & 63;
    int wm = wid >> 1, wn = wid & 1;
    int q = lane >> 4, l16 = lane & 15;
    int rbase0 = wid * 32;

    f32x4 acc[4][4];
#pragma unroll
    for (int mi = 0; mi < 4; mi++)
#pragma unroll
        for (int ni = 0; ni < 4; ni++) acc[mi][ni] = (f32x4){0.f, 0.f, 0.f, 0.f};

    __syncthreads();

    if constexpr (ASYNC) {
        // per-lane staging addresses: 8 rows/call, 128B contiguous per row,
        // global column pre-swizzled (slot ^ row&7), LDS dest linear.
        int rowoff = lane >> 3;              // 0..7 within the 8-row group
        int slot = lane & 7;                 // 16B slot within 128B segment
        int scol = ((slot ^ rowoff) << 3);   // swizzled u16 column
        const u16* gA = A + (s0 + rbase0 + rowoff) * KDIM + scol;
        const u16* gB = Bw + (long)(o0 + rbase0 + rowoff) * KDIM + scol;
        for (int kt = 0; kt < KDIM; kt += 64) {
#pragma unroll
            for (int gg = 0; gg < 4; gg++) {
                gl_lds16(gA + (long)gg * 8 * KDIM + kt, &Al[(rbase0 + gg * 8) * 64]);
                gl_lds16(gB + (long)gg * 8 * KDIM + kt, &Bl[(rbase0 + gg * 8) * 64]);
            }
            __syncthreads();
#pragma unroll
            for (int ks = 0; ks < 2; ks++) {
                bf16x8 af[4], bfr[4];
#pragma unroll
                for (int mi = 0; mi < 4; mi++) {
                    int row = wm * 64 + mi * 16 + l16;
                    af[mi] = *(const bf16x8*)&Al[row * 64 + (((ks * 4 + q) ^ (row & 7)) << 3)];
                }
#pragma unroll
                for (int ni = 0; ni < 4; ni++) {
                    int row = wn * 64 + ni * 16 + l16;
                    bfr[ni] = *(const bf16x8*)&Bl[row * 64 + (((ks * 4 + q) ^ (row & 7)) << 3)];
                }
#pragma unroll
                for (int mi = 0; mi < 4; mi++)
#pragma unroll
                    for (int ni = 0; ni < 4; ni++)
                        acc[mi][ni] = __builtin_amdgcn_mfma_f32_16x16x32_bf16(af[mi], bfr[ni],
                                                                              acc[mi][ni], 0, 0, 0);
            }
            __syncthreads();
        }
    } else {
        for (int kt = 0; kt < KDIM; kt += 32) {
#pragma unroll
            for (int cc = 0; cc < 2; cc++) {
                int ci = tid + cc * 256;
                int row = ci >> 2;
                int kc = (ci & 3) << 3;
                union { uint4 u; u16 h[8]; } va;
                va.u = *(const uint4*)(A + (s0 + row) * KDIM + kt + kc);
                if constexpr (BN_IN) {
#pragma unroll
                    for (int j = 0; j < 8; j++) {
                        float f = bf2f(va.h[j]);
                        f = fmaxf(fmaf(f, s_scale[kt + kc + j], s_shift[kt + kc + j]), 0.0f);
                        va.h[j] = f2bf(f);
                    }
                }
                *(uint4*)&Al[row * 40 + kc] = va.u;
                *(uint4*)&Bl[row * 40 + kc] = *(const uint4*)(Bw + (long)(o0 + row) * KDIM + kt + kc);
            }
            __syncthreads();
            bf16x8 af[4], bfr[4];
#pragma unroll
            for (int mi = 0; mi < 4; mi++)
                af[mi] = *(const bf16x8*)&Al[(wm * 64 + mi * 16 + l16) * 40 + q * 8];
#pragma unroll
            for (int ni = 0; ni < 4; ni++)
                bfr[ni] = *(const bf16x8*)&Bl[(wn * 64 + ni * 16 + l16) * 40 + q * 8];
#pragma unroll
            for (int mi = 0; mi < 4; mi++)
#pragma unroll
                for (int ni = 0; ni < 4; ni++)
                    acc[mi][ni] = __builtin_amdgcn_mfma_f32_16x16x32_bf16(af[mi], bfr[ni],
                                                                          acc[mi][ni], 0, 0, 0);
            __syncthreads();
        }
    }

#pragma unroll
    for (int ni = 0; ni < 4; ni++) {
        int coll = wn * 64 + ni * 16 + l16;
        int col = o0 + coll;
        float bz = bias[col];
        float s1 = 0.0f, s2 = 0.0f;
#pragma unroll
        for (int mi = 0; mi < 4; mi++) {
#pragma unroll
            for (int r = 0; r < 4; r++) {
                float v = acc[mi][ni][r] + bz;
                s1 += v;
                s2 += v * v;
                long row = s0 + wm * 64 + mi * 16 + q * 4 + r;
                Yout[row * Ntot + col] = f2bf(v);
            }
        }
        s1 += __shfl_xor(s1, 16, 64);
        s1 += __shfl_xor(s1, 32, 64);
        s2 += __shfl_xor(s2, 16, 64);
        s2 += __shfl_xor(s2, 32, 64);
        if (q == 0) {
            atomicAdd(&s_stats[coll], s1);
            atomicAdd(&s_stats[128 + coll], s2);
        }
    }
    __syncthreads();
    if (tid < 128) {
        atomicAdd(&g_out_sum[o0 + tid], s_stats[tid]);
        atomicAdd(&g_out_ssq[o0 + tid], s_stats[128 + tid]);
    }
}

// ---------------------------------------------------------------------------
// final BN+ReLU + transpose to [B][128][N1] fp32 (Y1 bf16, 16B reads)
// ---------------------------------------------------------------------------
__global__ __launch_bounds__(256) void finalize_k(const u16* __restrict__ Y1,
                                                  const float* __restrict__ g_sum,
                                                  const float* __restrict__ g_ssq,
                                                  const float* __restrict__ gamma,
                                                  const float* __restrict__ beta,
                                                  float* __restrict__ out) {
    __shared__ float s_scale[128], s_shift[128];
    int tid = threadIdx.x;
    if (tid < 128) {
        float mu = g_sum[tid] * (1.0f / 65536.0f);
        float var = g_ssq[tid] * (1.0f / 65536.0f) - mu * mu;
        float rs = rsqrtf(var + 1e-5f);
        float sc = gamma[tid] * rs;
        s_scale[tid] = sc;
        s_shift[tid] = beta[tid] - mu * sc;
    }
    __syncthreads();
    long s = (long)blockIdx.x * 256 + tid;
    int b = (int)(s >> 13);
    int n = (int)(s & 8191);
    const u16* yrow = Y1 + s * 128;
    float* obase = out + (long)b * 128 * 8192 + n;
#pragma unroll
    for (int oc = 0; oc < 128; oc += 8) {
        union { uint4 u; u16 h[8]; } va;
        va.u = *(const uint4*)&yrow[oc];
#pragma unroll
        for (int k = 0; k < 8; k++) {
            int o = oc + k;
            float v = fmaxf(fmaf(bf2f(va.h[k]), s_scale[o], s_shift[o]), 0.0f);
            obase[(long)o * 8192] = v;
        }
    }
}

// ---------------------------------------------------------------------------
// launch (5 dispatches)
// ---------------------------------------------------------------------------
extern "C" void kernel_launch(void* const* d_in, const int* in_sizes, int n_in,
                              void* d_out, int out_size, void* d_ws, size_t ws_size,
                              hipStream_t stream) {
    const float* xyz1    = (const float*)d_in[0];
    const float* xyz2    = (const float*)d_in[1];
    const float* points1 = (const float*)d_in[2];
    const float* points2 = (const float*)d_in[3];
    const float* w0 = (const float*)d_in[4];
    const float* b0 = (const float*)d_in[5];
    const float* gamma0 = (const float*)d_in[6];
    const float* beta0 = (const float*)d_in[7];
    const float* w1 = (const float*)d_in[8];
    const float* b1 = (const float*)d_in[9];
    const float* gamma1 = (const float*)d_in[10];
    const float* beta1 = (const float*)d_in[11];
    float* out = (float*)d_out;

    char* ws = (char*)d_ws;
    u16* X       = (u16*)(ws + 0);             // 65536 x 384 bf16 = 50,331,648
    u16* P2T     = (u16*)(ws + 50331648);      // 8,388,608
    u16* w0b     = (u16*)(ws + 58720256);      // 196,608
    u16* w1b     = (u16*)(ws + 58916864);      // 65,536
    u16* Y0      = (u16*)(ws + 58982400);      // 33,554,432
    u16* Y1b     = (u16*)(ws + 92536832);      // 16,777,216
    float* stats = (float*)(ws + 109314048);   // 3,072
    if (ws_size < 109317120) return;
    float* gsum0 = stats;
    float* gss0  = stats + 256;
    float* gsum1 = stats + 512;
    float* gss1  = stats + 640;

    preproc<<<4609, 256, 0, stream>>>(w0, w1, points2, w0b, w1b, P2T, stats);
    knn_interp<<<dim3(128, 8), 512, 0, stream>>>(xyz1, xyz2, points1, P2T, X);
    gemm_bn<384, false, true, true><<<1024, 256, 0, stream>>>(
        X, w0b, b0, nullptr, nullptr, nullptr, nullptr, Y0, 256, gsum0, gss0);
    gemm_bn<256, true, false, false><<<dim3(1, 512), 256, 0, stream>>>(
        Y0, w1b, b1, gsum0, gss0, gamma0, beta0, Y1b, 128, gsum1, gss1);
    finalize_k<<<256, 256, 0, stream>>>(Y1b, gsum1, gss1, gamma1, beta1, out);
}

// Round 13
// 243.076 us; speedup vs baseline: 1.1654x; 1.0213x over previous
//
#include <hip/hip_runtime.h>
#include <cstdint>

using u16 = unsigned short;
typedef short bf16x8 __attribute__((ext_vector_type(8)));
typedef float f32x4 __attribute__((ext_vector_type(4)));

__device__ __forceinline__ float bf2f(u16 h) {
    union { unsigned u; float f; } x;
    x.u = ((unsigned)h) << 16;
    return x.f;
}
__device__ __forceinline__ u16 f2bf(float f) {
    union { float f; unsigned u; } x;
    x.f = f;
    unsigned r = x.u + 0x7fffu + ((x.u >> 16) & 1u);
    return (u16)(r >> 16);
}

// async global->LDS, 16B per lane; LDS dest is wave-uniform base + lane*16
__device__ __forceinline__ void gl_lds16(const u16* g, u16* l) {
    __builtin_amdgcn_global_load_lds((const __attribute__((address_space(1))) void*)g,
                                     (__attribute__((address_space(3))) void*)l, 16, 0, 0);
}

#define N1 8192
#define N2 2048
#define C2 256

// ---------------------------------------------------------------------------
// preproc (R17): points2 transpose + w0/w1 cvt + stats zero.
// ---------------------------------------------------------------------------
__device__ __forceinline__ void tr_tile(const float* __restrict__ src,
                                        u16* __restrict__ dst,
                                        int C, int N, int ds, int b, int n0, int c0,
                                        int tid, float (*tile)[33]) {
    int tx = tid & 31, ty = tid >> 5;  // 32 x 8
    const float* s = src + (long)b * C * N;
#pragma unroll
    for (int i = 0; i < 4; i++) {
        int c = ty + i * 8;
        tile[c][tx] = s[(long)(c0 + c) * N + n0 + tx];
    }
    __syncthreads();
    u16* d = dst + (long)b * N * ds;
#pragma unroll
    for (int i = 0; i < 4; i++) {
        int n = ty + i * 8;
        d[(long)(n0 + n) * ds + c0 + tx] = f2bf(tile[tx][n]);
    }
}

__global__ __launch_bounds__(256) void preproc(const float* __restrict__ w0,
                                               const float* __restrict__ w1,
                                               const float* __restrict__ points2,
                                               u16* __restrict__ w0b,
                                               u16* __restrict__ w1b,
                                               u16* __restrict__ P2T,
                                               float* __restrict__ stats) {
    __shared__ float tile[32][33];
    int bid = blockIdx.x, tid = threadIdx.x;
    if (bid < 4096) {
        int nb = bid & 63, cb = (bid >> 6) & 7, b = bid >> 9;
        tr_tile(points2, P2T, 256, 2048, 256, b, nb * 32, cb * 32, tid, tile);
    } else if (bid < 4480) {
        int i = (bid - 4096) * 256 + tid;
        w0b[i] = f2bf(w0[i]);
    } else if (bid < 4608) {
        int i = (bid - 4480) * 256 + tid;
        w1b[i] = f2bf(w1[i]);
    } else {
        for (int i = tid; i < 768; i += 256) stats[i] = 0.0f;
    }
}

// ---------------------------------------------------------------------------
// kNN(3) + interpolation — R17 FROZEN (242.9 µs config): scan/merge/gather
// = R9 verbatim + fused points1->X copy (stride-65 LDS staging).
// ---------------------------------------------------------------------------
__global__ __launch_bounds__(512) void knn_interp(const float* __restrict__ xyz1,
                                                  const float* __restrict__ xyz2,
                                                  const float* __restrict__ points1,
                                                  const u16* __restrict__ P2T,  // [B][N2][C2]
                                                  u16* __restrict__ X) {       // [B*N1][384]
    __shared__ float4 pts[N2 / 2 + 16];  // 16640 B (scan stage; reused as p1 tile, stride-65)
    __shared__ float m_d[8][64][3];      // 6144 B partial top-3 (squared dist)
    __shared__ int   m_i[8][64][3];      // 6144 B
    __shared__ int   s_idx[64][3];
    __shared__ float s_w[64][3];
    int b = blockIdx.y;
    int n0 = blockIdx.x * 64;
    int tid = threadIdx.x;
    int ql = tid & 63;       // query within block
    int part = tid >> 6;     // candidate partition 0..7 (== wave id)

    int cp = tid >> 3;       // channel pair: channels 2cp, 2cp+1
    int g = tid & 7;         // n-octet within the 64-query tile
    const float* p1r0 = points1 + ((long)b * 128 + 2 * cp) * N1 + n0 + g * 8;
    const float* p1r1 = p1r0 + N1;
    float4 c0a = *(const float4*)(p1r0);
    float4 c0b = *(const float4*)(p1r0 + 4);
    float4 c1a = *(const float4*)(p1r1);
    float4 c1b = *(const float4*)(p1r1 + 4);
    asm volatile("" ::: "memory");

    int n = n0 + ql;
    float px = xyz1[((long)b * N1 + n) * 3 + 0];
    float py = xyz1[((long)b * N1 + n) * 3 + 1];
    float pz = xyz1[((long)b * N1 + n) * 3 + 2];
    float psq = __fadd_rn(__fadd_rn(__fmul_rn(px, px), __fmul_rn(py, py)), __fmul_rn(pz, pz));

    float b0 = 1e30f, b1 = 1e30f, b2 = 1e30f;
    int i0 = 0, i1 = 0, i2 = 0;

    for (int half = 0; half < 2; half++) {
        for (int j = tid; j < N2 / 2; j += 512) {
            int jg = half * (N2 / 2) + j;
            float x = xyz2[((long)b * N2 + jg) * 3 + 0];
            float y = xyz2[((long)b * N2 + jg) * 3 + 1];
            float z = xyz2[((long)b * N2 + jg) * 3 + 2];
            float nsq = __fadd_rn(__fadd_rn(__fmul_rn(x, x), __fmul_rn(y, y)), __fmul_rn(z, z));
            pts[j] = make_float4(x, y, z, nsq);
        }
        __syncthreads();

        int jbeg = half * (N2 / 2) + part * (N2 / 16);
        const float4* lp = &pts[part * (N2 / 16)];
#pragma unroll 8
        for (int jj = 0; jj < N2 / 16; jj++) {
            int j = jbeg + jj;
            float4 p = lp[jj];  // wave-uniform -> LDS broadcast
            float dot = __fadd_rn(__fadd_rn(__fmul_rn(px, p.x), __fmul_rn(py, p.y)),
                                  __fmul_rn(pz, p.z));
            float sq = __fsub_rn(__fadd_rn(psq, p.w), __fmul_rn(2.0f, dot));
            if (sq < b2) {
                if (sq < b1) {
                    b2 = b1; i2 = i1;
                    if (sq < b0) { b1 = b0; i1 = i0; b0 = sq; i0 = j; }
                    else         { b1 = sq; i1 = j; }
                } else { b2 = sq; i2 = j; }
            }
        }
        __syncthreads();  // scan done before half re-stage
    }

    m_d[part][ql][0] = b0; m_d[part][ql][1] = b1; m_d[part][ql][2] = b2;
    m_i[part][ql][0] = i0; m_i[part][ql][1] = i1; m_i[part][ql][2] = i2;
    __syncthreads();

    // ---- stage p1 tile into pts-alias (dead after scan), stride 65 u32 ----
    {
        unsigned* t32 = (unsigned*)pts;  // [64] rows x stride-65 u32, col = cp
        float r0[8] = {c0a.x, c0a.y, c0a.z, c0a.w, c0b.x, c0b.y, c0b.z, c0b.w};
        float r1[8] = {c1a.x, c1a.y, c1a.z, c1a.w, c1b.x, c1b.y, c1b.z, c1b.w};
#pragma unroll
        for (int k = 0; k < 8; k++) {
            unsigned v = (unsigned)f2bf(r0[k]) | ((unsigned)f2bf(r1[k]) << 16);
            t32[(g * 8 + k) * 65 + cp] = v;
        }
    }

    if (tid < 64) {
        float c0 = 1e30f, c1 = 1e30f, c2 = 1e30f;
        int a0 = 0x7fffffff, a1 = 0x7fffffff, a2 = 0x7fffffff;
#pragma unroll
        for (int pp = 0; pp < 8; pp++) {
#pragma unroll
            for (int k = 0; k < 3; k++) {
                float d = m_d[pp][tid][k];
                int ix = m_i[pp][tid][k];
                if (d < c2 || (d == c2 && ix < a2)) {
                    if (d < c1 || (d == c1 && ix < a1)) {
                        c2 = c1; a2 = a1;
                        if (d < c0 || (d == c0 && ix < a0)) { c1 = c0; a1 = a0; c0 = d; a0 = ix; }
                        else                                { c1 = d; a1 = ix; }
                    } else { c2 = d; a2 = ix; }
                }
            }
        }
        float e0 = sqrtf(fmaxf(c0, 0.0f));
        float e1 = sqrtf(fmaxf(c1, 0.0f));
        float e2 = sqrtf(fmaxf(c2, 0.0f));
        float kd0 = fmaxf(e0, 1e-10f), kd1 = fmaxf(e1, 1e-10f), kd2 = fmaxf(e2, 1e-10f);
        float w0 = __fdiv_rn(1.0f, kd0), w1 = __fdiv_rn(1.0f, kd1), w2 = __fdiv_rn(1.0f, kd2);
        float wsum = __fadd_rn(__fadd_rn(w0, w1), w2);
        s_idx[tid][0] = a0; s_idx[tid][1] = a1; s_idx[tid][2] = a2;
        s_w[tid][0] = __fdiv_rn(w0, wsum);
        s_w[tid][1] = __fdiv_rn(w1, wsum);
        s_w[tid][2] = __fdiv_rn(w2, wsum);
    }
    __syncthreads();

    // ---- coalesced X[:,0:128] store ----
    {
        const unsigned* t32 = (const unsigned*)pts;
        int p = tid >> 3, ch = tid & 7;
        unsigned v[8];
#pragma unroll
        for (int j = 0; j < 8; j++) v[j] = t32[p * 65 + ch * 8 + j];
        uint4* xo = (uint4*)(X + (long)(b * N1 + n0 + p) * 384);
        xo[ch * 2]     = make_uint4(v[0], v[1], v[2], v[3]);
        xo[ch * 2 + 1] = make_uint4(v[4], v[5], v[6], v[7]);
    }

    int l = tid & 63;
    const u16* base = P2T + (long)b * N2 * C2;
#pragma unroll 2
    for (int p = part; p < 64; p += 8) {
        int j0 = s_idx[p][0], j1 = s_idx[p][1], j2 = s_idx[p][2];  // broadcast
        float f0 = s_w[p][0], f1 = s_w[p][1], f2 = s_w[p][2];
        ushort4 r0 = *(const ushort4*)&base[(long)j0 * C2 + l * 4];
        ushort4 r1 = *(const ushort4*)&base[(long)j1 * C2 + l * 4];
        ushort4 r2 = *(const ushort4*)&base[(long)j2 * C2 + l * 4];
        ushort4 o;
        o.x = f2bf(__fadd_rn(__fadd_rn(__fmul_rn(bf2f(r0.x), f0), __fmul_rn(bf2f(r1.x), f1)),
                             __fmul_rn(bf2f(r2.x), f2)));
        o.y = f2bf(__fadd_rn(__fadd_rn(__fmul_rn(bf2f(r0.y), f0), __fmul_rn(bf2f(r1.y), f1)),
                             __fmul_rn(bf2f(r2.y), f2)));
        o.z = f2bf(__fadd_rn(__fadd_rn(__fmul_rn(bf2f(r0.z), f0), __fmul_rn(bf2f(r1.z), f1)),
                             __fmul_rn(bf2f(r2.z), f2)));
        o.w = f2bf(__fadd_rn(__fadd_rn(__fmul_rn(bf2f(r0.w), f0), __fmul_rn(bf2f(r1.w), f1)),
                             __fmul_rn(bf2f(r2.w), f2)));
        *(ushort4*)&X[(long)(b * N1 + n0 + p) * 384 + 128 + l * 4] = o;
    }
}

// ---------------------------------------------------------------------------
// bf16 MFMA GEMM — R17 VERBATIM (best measured: 242.9 µs total).
// ASYNC (gemm0): BK=64 two-sub gl_lds16 staging, SWZ XCD pairing. Ledger:
// R19 vmcnt pipeline neutral-negative; R21 coalesced+XOR-swizzle staging
// neutral-negative — gemm0 staging micro-opts are exhausted (3 variants tie).
// Non-ASYNC (gemm1): BK=32 VGPR staging + fused input BN+ReLU (stride-40).
// R18/R20 grid-barrier fusion abandoned (spin cost ~50µs at any occupancy).
// ---------------------------------------------------------------------------
template <int KDIM, bool BN_IN, bool ASYNC, bool SWZ>
__global__ __launch_bounds__(256) void gemm_bn(const u16* __restrict__ A,
                                               const u16* __restrict__ Bw,
                                               const float* __restrict__ bias,
                                               const float* __restrict__ g_in_sum,
                                               const float* __restrict__ g_in_ssq,
                                               const float* __restrict__ gamma_in,
                                               const float* __restrict__ beta_in,
                                               u16* __restrict__ Yout, int Ntot,
                                               float* __restrict__ g_out_sum,
                                               float* __restrict__ g_out_ssq) {
    constexpr int LDSZ = ASYNC ? 2 * 128 * 32 : 128 * 40;  // u16 elems
    constexpr int SUB = 128 * 32;                          // sub-tile size (ASYNC)
    __shared__ __align__(16) u16 Al[LDSZ];
    __shared__ __align__(16) u16 Bl[LDSZ];
    __shared__ float s_stats[256];
    __shared__ float s_scale[BN_IN ? KDIM : 2];
    __shared__ float s_shift[BN_IN ? KDIM : 2];

    int tid = threadIdx.x;
    long s0;
    int o0;
    if constexpr (SWZ) {
        int bid = blockIdx.x;
        int xcd = bid & 7;
        int i = bid >> 3;               // 0..127 within XCD
        int u = xcd * 64 + (i >> 1);    // pair (row-tile) id 0..511
        s0 = (long)u * 128;
        o0 = (i & 1) * 128;
    } else {
        s0 = (long)blockIdx.y * 128;    // row tile
        o0 = blockIdx.x * 128;          // col tile
    }

    s_stats[tid] = 0.0f;
    if constexpr (BN_IN) {
        for (int k = tid; k < KDIM; k += 256) {
            float mu = g_in_sum[k] * (1.0f / 65536.0f);
            float var = g_in_ssq[k] * (1.0f / 65536.0f) - mu * mu;
            float rs = rsqrtf(var + 1e-5f);
            float sc = gamma_in[k] * rs;
            s_scale[k] = sc;
            s_shift[k] = beta_in[k] - mu * sc;
        }
    }
    int wid = tid >> 6, lane = tid & 63;
    int wm = wid >> 1, wn = wid & 1;
    int q = lane >> 4, l16 = lane & 15;

    f32x4 acc[4][4];
#pragma unroll
    for (int mi = 0; mi < 4; mi++)
#pragma unroll
        for (int ni = 0; ni < 4; ni++) acc[mi][ni] = (f32x4){0.f, 0.f, 0.f, 0.f};

    int rbase0 = wid * 32;
    int rsub = lane >> 2;
    int colsw = (((lane & 3) ^ (rsub & 3)) << 3);
    const u16* gA0 = A + (s0 + rbase0 + rsub) * KDIM + colsw;
    const u16* gA1 = gA0 + (long)16 * KDIM;
    const u16* gB0 = Bw + (long)(o0 + rbase0 + rsub) * KDIM + colsw;
    const u16* gB1 = gB0 + (long)16 * KDIM;
    u16* lA0 = &Al[rbase0 * 32];
    u16* lA1 = &Al[(rbase0 + 16) * 32];
    u16* lB0 = &Bl[rbase0 * 32];
    u16* lB1 = &Bl[(rbase0 + 16) * 32];
    int qA = ASYNC ? (q ^ (l16 & 3)) : q;

    __syncthreads();

    if constexpr (ASYNC) {
        for (int kt = 0; kt < KDIM; kt += 64) {
#pragma unroll
            for (int sub = 0; sub < 2; sub++) {
                int ko = kt + sub * 32;
                gl_lds16(gA0 + ko, lA0 + sub * SUB);
                gl_lds16(gA1 + ko, lA1 + sub * SUB);
                gl_lds16(gB0 + ko, lB0 + sub * SUB);
                gl_lds16(gB1 + ko, lB1 + sub * SUB);
            }
            __syncthreads();
#pragma unroll
            for (int sub = 0; sub < 2; sub++) {
                bf16x8 af[4], bfr[4];
#pragma unroll
                for (int mi = 0; mi < 4; mi++)
                    af[mi] = *(const bf16x8*)&Al[sub * SUB + (wm * 64 + mi * 16 + l16) * 32 + qA * 8];
#pragma unroll
                for (int ni = 0; ni < 4; ni++)
                    bfr[ni] = *(const bf16x8*)&Bl[sub * SUB + (wn * 64 + ni * 16 + l16) * 32 + qA * 8];
#pragma unroll
                for (int mi = 0; mi < 4; mi++)
#pragma unroll
                    for (int ni = 0; ni < 4; ni++)
                        acc[mi][ni] = __builtin_amdgcn_mfma_f32_16x16x32_bf16(af[mi], bfr[ni],
                                                                              acc[mi][ni], 0, 0, 0);
            }
            __syncthreads();
        }
    } else {
        for (int kt = 0; kt < KDIM; kt += 32) {
#pragma unroll
            for (int cc = 0; cc < 2; cc++) {
                int ci = tid + cc * 256;
                int row = ci >> 2;
                int kc = (ci & 3) << 3;
                union { uint4 u; u16 h[8]; } va;
                va.u = *(const uint4*)(A + (s0 + row) * KDIM + kt + kc);
                if constexpr (BN_IN) {
#pragma unroll
                    for (int j = 0; j < 8; j++) {
                        float f = bf2f(va.h[j]);
                        f = fmaxf(fmaf(f, s_scale[kt + kc + j], s_shift[kt + kc + j]), 0.0f);
                        va.h[j] = f2bf(f);
                    }
                }
                *(uint4*)&Al[row * 40 + kc] = va.u;
                *(uint4*)&Bl[row * 40 + kc] = *(const uint4*)(Bw + (long)(o0 + row) * KDIM + kt + kc);
            }
            __syncthreads();
            bf16x8 af[4], bfr[4];
#pragma unroll
            for (int mi = 0; mi < 4; mi++)
                af[mi] = *(const bf16x8*)&Al[(wm * 64 + mi * 16 + l16) * 40 + qA * 8];
#pragma unroll
            for (int ni = 0; ni < 4; ni++)
                bfr[ni] = *(const bf16x8*)&Bl[(wn * 64 + ni * 16 + l16) * 40 + qA * 8];
#pragma unroll
            for (int mi = 0; mi < 4; mi++)
#pragma unroll
                for (int ni = 0; ni < 4; ni++)
                    acc[mi][ni] = __builtin_amdgcn_mfma_f32_16x16x32_bf16(af[mi], bfr[ni],
                                                                          acc[mi][ni], 0, 0, 0);
            __syncthreads();
        }
    }

#pragma unroll
    for (int ni = 0; ni < 4; ni++) {
        int coll = wn * 64 + ni * 16 + l16;
        int col = o0 + coll;
        float bz = bias[col];
        float s1 = 0.0f, s2 = 0.0f;
#pragma unroll
        for (int mi = 0; mi < 4; mi++) {
#pragma unroll
            for (int r = 0; r < 4; r++) {
                float v = acc[mi][ni][r] + bz;
                s1 += v;
                s2 += v * v;
                long row = s0 + wm * 64 + mi * 16 + q * 4 + r;
                Yout[row * Ntot + col] = f2bf(v);
            }
        }
        s1 += __shfl_xor(s1, 16, 64);
        s1 += __shfl_xor(s1, 32, 64);
        s2 += __shfl_xor(s2, 16, 64);
        s2 += __shfl_xor(s2, 32, 64);
        if (q == 0) {
            atomicAdd(&s_stats[coll], s1);
            atomicAdd(&s_stats[128 + coll], s2);
        }
    }
    __syncthreads();
    if (tid < 128) {
        atomicAdd(&g_out_sum[o0 + tid], s_stats[tid]);
        atomicAdd(&g_out_ssq[o0 + tid], s_stats[128 + tid]);
    }
}

// ---------------------------------------------------------------------------
// final BN+ReLU + transpose to [B][128][N1] fp32 (Y1 bf16, 16B reads)
// ---------------------------------------------------------------------------
__global__ __launch_bounds__(256) void finalize_k(const u16* __restrict__ Y1,
                                                  const float* __restrict__ g_sum,
                                                  const float* __restrict__ g_ssq,
                                                  const float* __restrict__ gamma,
                                                  const float* __restrict__ beta,
                                                  float* __restrict__ out) {
    __shared__ float s_scale[128], s_shift[128];
    int tid = threadIdx.x;
    if (tid < 128) {
        float mu = g_sum[tid] * (1.0f / 65536.0f);
        float var = g_ssq[tid] * (1.0f / 65536.0f) - mu * mu;
        float rs = rsqrtf(var + 1e-5f);
        float sc = gamma[tid] * rs;
        s_scale[tid] = sc;
        s_shift[tid] = beta[tid] - mu * sc;
    }
    __syncthreads();
    long s = (long)blockIdx.x * 256 + tid;
    int b = (int)(s >> 13);
    int n = (int)(s & 8191);
    const u16* yrow = Y1 + s * 128;
    float* obase = out + (long)b * 128 * 8192 + n;
#pragma unroll
    for (int oc = 0; oc < 128; oc += 8) {
        union { uint4 u; u16 h[8]; } va;
        va.u = *(const uint4*)&yrow[oc];
#pragma unroll
        for (int k = 0; k < 8; k++) {
            int o = oc + k;
            float v = fmaxf(fmaf(bf2f(va.h[k]), s_scale[o], s_shift[o]), 0.0f);
            obase[(long)o * 8192] = v;
        }
    }
}

// ---------------------------------------------------------------------------
// launch (5 dispatches)
// ---------------------------------------------------------------------------
extern "C" void kernel_launch(void* const* d_in, const int* in_sizes, int n_in,
                              void* d_out, int out_size, void* d_ws, size_t ws_size,
                              hipStream_t stream) {
    const float* xyz1    = (const float*)d_in[0];
    const float* xyz2    = (const float*)d_in[1];
    const float* points1 = (const float*)d_in[2];
    const float* points2 = (const float*)d_in[3];
    const float* w0 = (const float*)d_in[4];
    const float* b0 = (const float*)d_in[5];
    const float* gamma0 = (const float*)d_in[6];
    const float* beta0 = (const float*)d_in[7];
    const float* w1 = (const float*)d_in[8];
    const float* b1 = (const float*)d_in[9];
    const float* gamma1 = (const float*)d_in[10];
    const float* beta1 = (const float*)d_in[11];
    float* out = (float*)d_out;

    char* ws = (char*)d_ws;
    u16* X       = (u16*)(ws + 0);             // 65536 x 384 bf16 = 50,331,648
    u16* P2T     = (u16*)(ws + 50331648);      // 8,388,608
    u16* w0b     = (u16*)(ws + 58720256);      // 196,608
    u16* w1b     = (u16*)(ws + 58916864);      // 65,536
    u16* Y0      = (u16*)(ws + 58982400);      // 33,554,432
    u16* Y1b     = (u16*)(ws + 92536832);      // 16,777,216
    float* stats = (float*)(ws + 109314048);   // 3,072
    if (ws_size < 109317120) return;
    float* gsum0 = stats;
    float* gss0  = stats + 256;
    float* gsum1 = stats + 512;
    float* gss1  = stats + 640;

    preproc<<<4609, 256, 0, stream>>>(w0, w1, points2, w0b, w1b, P2T, stats);
    knn_interp<<<dim3(128, 8), 512, 0, stream>>>(xyz1, xyz2, points1, P2T, X);
    gemm_bn<384, false, true, true><<<1024, 256, 0, stream>>>(
        X, w0b, b0, nullptr, nullptr, nullptr, nullptr, Y0, 256, gsum0, gss0);
    gemm_bn<256, true, false, false><<<dim3(1, 512), 256, 0, stream>>>(
        Y0, w1b, b1, gsum0, gss0, gamma0, beta0, Y1b, 128, gsum1, gss1);
    finalize_k<<<256, 256, 0, stream>>>(Y1b, gsum1, gss1, gamma1, beta1, out);
}